// Round 7
// baseline (228.680 us; speedup 1.0000x reference)
//
#include <hip/hip_runtime.h>
#include <hip/hip_bf16.h>
#include <stdint.h>

typedef __attribute__((ext_vector_type(8))) short short8;
typedef __attribute__((ext_vector_type(4))) short short4v;
typedef __attribute__((ext_vector_type(4))) float floatx4;
typedef __attribute__((ext_vector_type(4))) unsigned int uint4v;
typedef unsigned long long u64;

typedef __attribute__((address_space(1))) const uint32_t ga_u32;
typedef __attribute__((address_space(3))) uint32_t ls_u32;

static constexpr int NROWS = 32768;
static constexpr int NCODE = 8192;
static constexpr int QELEMS = 8388608;

static __device__ __forceinline__ short bf16bits(float v) {
  __hip_bfloat16 h = __float2bfloat16(v);
  return *reinterpret_cast<short*>(&h);
}

// ---- fused prep: [0,1024) z-transpose, [1024,3072) codebook, [3072,3088) amin init ----
__global__ __launch_bounds__(256) void prep_all(
    const float* __restrict__ z, const float* __restrict__ cb,
    __hip_bfloat16* __restrict__ zh, __hip_bfloat16* __restrict__ chv,
    float* __restrict__ norms, u64* __restrict__ amin)
{
  const int bid = blockIdx.x;
  const int t = threadIdx.x;
  if (bid < 1024) {
    __shared__ float tile[32][260];
    const int b = bid & 31, db = (bid >> 5) & 7, hwb = bid >> 8;
    const int d0 = db * 32, hw0 = hwb * 256;
    const float* src = z + (((size_t)b * 256 + d0) << 10) + hw0;
#pragma unroll
    for (int i = 0; i < 8; ++i) {
      int idx = i * 256 + t;
      int r = idx >> 6, c4 = (idx & 63) * 4;
      *(floatx4*)&tile[r][c4] = *(const floatx4*)&src[((size_t)r << 10) + c4];
    }
    __syncthreads();
    const int dq = t & 3;
    const int hb = t >> 2;
#pragma unroll
    for (int it = 0; it < 4; ++it) {
      int h = hb + it * 64;
      short8 o;
#pragma unroll
      for (int i = 0; i < 8; ++i) o[i] = bf16bits(tile[dq * 8 + i][h]);
      *(short8*)&zh[((size_t)(b * 1024 + hw0 + h)) * 256 + d0 + dq * 8] = o;
    }
  } else if (bid < 3072) {
    const int k = (bid - 1024) * 4 + (t >> 6);
    const int lane = t & 63;
    floatx4 v = *(const floatx4*)&cb[((size_t)k << 8) + lane * 4];
    short4v o;
#pragma unroll
    for (int i = 0; i < 4; ++i) o[i] = bf16bits(v[i]);
    *(short4v*)&chv[((size_t)k << 8) + lane * 4] = o;
    float s = v[0] * v[0] + v[1] * v[1] + v[2] * v[2] + v[3] * v[3];
#pragma unroll
    for (int off = 32; off; off >>= 1) s += __shfl_down(s, off);
    if (lane == 0) norms[k] = s;
  } else {
    const int base = (bid - 3072) * 2048;
#pragma unroll
    for (int i = 0; i < 8; ++i) amin[base + i * 256 + t] = ~0ull;
  }
}

// ---- main: 256x256 tile, 8 waves, 4-slot ring, frag read-ahead 1 K-tile ----
// Body kt: ds_read frags(kt+1) into bank[~kt] (overlaps MFMA(kt) on the port),
// issue STAGE(kt+3), MFMA(kt) from bank[kt] (lgkm already drained -> counted
// wait), vmcnt(4) boundary (stage(kt+2) drained, stage(kt+3) in flight).
__global__ __launch_bounds__(512, 2) void gemm_argmin(
    const __hip_bfloat16* __restrict__ zh, const __hip_bfloat16* __restrict__ chv,
    const float* __restrict__ norms, u64* __restrict__ amin)
{
  // 4 slots x 32 KiB: A[256][32] at +0 (8192 ush), B[256][32] at +8192
  __shared__ alignas(16) unsigned short lds[4 * 16384];

  const int tid = threadIdx.x;
  const int lane = tid & 63;
  const int wid = tid >> 6;
  const int wm = wid >> 2;  // code half (128 codes)
  const int wn = wid & 3;   // zrow quarter (64 zrows)

  // XCD chunked swizzle: nwg = 4096 (%8 == 0)
  const int bid = blockIdx.x;
  const int swz = (bid & 7) * 512 + (bid >> 3);
  const int cx = swz & 31;   // code block (32)
  const int cy = swz >> 5;   // zrow block (128)
  const int m0 = cx * 256;
  const int n0 = cy * 256;

  const int q = lane & 15;
  const int g = lane >> 4;
  const int rchunk = ((g ^ ((q >> 1) & 3)) << 3);  // swizzled chunk (ushort units)

  // staging: linear LDS dest (tid*16B), chunk-XOR pre-swizzled global source
  const int stRow = tid >> 2;                               // 0..127
  const int stKoff = (((tid & 3) ^ ((tid >> 3) & 3)) << 3); // swizzled k-elem offset

  floatx4 acc[8][4];
#pragma unroll
  for (int i = 0; i < 8; ++i)
#pragma unroll
    for (int j = 0; j < 4; ++j)
      acc[i][j] = (floatx4){0.f, 0.f, 0.f, 0.f};

  auto STAGE = [&](int kt) {  // 4 x global_load_lds(16B): A 16KB + B 16KB
    const int slot = kt & 3;
    unsigned short* sA = lds + slot * 16384 + tid * 8;
    const __hip_bfloat16* gA = chv + ((size_t)(m0 + stRow) << 8) + kt * 32 + stKoff;
    __builtin_amdgcn_global_load_lds((ga_u32*)gA, (ls_u32*)sA, 16, 0, 0);
    __builtin_amdgcn_global_load_lds((ga_u32*)(gA + (128 << 8)), (ls_u32*)(sA + 4096), 16, 0, 0);
    unsigned short* sB = lds + slot * 16384 + 8192 + tid * 8;
    const __hip_bfloat16* gB = zh + ((size_t)(n0 + stRow) << 8) + kt * 32 + stKoff;
    __builtin_amdgcn_global_load_lds((ga_u32*)gB, (ls_u32*)sB, 16, 0, 0);
    __builtin_amdgcn_global_load_lds((ga_u32*)(gB + (128 << 8)), (ls_u32*)(sB + 4096), 16, 0, 0);
  };
  auto LDA = [&](int slot, int i) -> short8 {
    int row = wm * 128 + i * 16 + q;
    return *(const short8*)(lds + slot * 16384 + row * 32 + rchunk);
  };
  auto LDB = [&](int slot, int j) -> short8 {
    int row = wn * 64 + j * 16 + q;
    return *(const short8*)(lds + slot * 16384 + 8192 + row * 32 + rchunk);
  };

  // prologue: stage kt 0,1,2; drain 0,1 (stage 2's 4 loads stay in flight)
  STAGE(0); STAGE(1); STAGE(2);
  asm volatile("s_waitcnt vmcnt(4)" ::: "memory");
  __builtin_amdgcn_s_barrier();
  asm volatile("" ::: "memory");

  short8 afr[2][8], bfr[2][4];
#pragma unroll
  for (int i = 0; i < 8; ++i) afr[0][i] = LDA(0, i);
#pragma unroll
  for (int j = 0; j < 4; ++j) bfr[0][j] = LDB(0, j);

#pragma unroll
  for (int kt = 0; kt < 8; ++kt) {
    const int cbk = kt & 1, nbk = (kt + 1) & 1;
    // read-ahead: frags(kt+1) (port works during this body's MFMA window)
    if (kt < 7) {
      const int ns = (kt + 1) & 3;
#pragma unroll
      for (int i = 0; i < 8; ++i) afr[nbk][i] = LDA(ns, i);
#pragma unroll
      for (int j = 0; j < 4; ++j) bfr[nbk][j] = LDB(ns, j);
    }
    if (kt + 3 < 8) STAGE(kt + 3);
    __builtin_amdgcn_s_setprio(1);
#pragma unroll
    for (int i = 0; i < 8; ++i)
#pragma unroll
      for (int j = 0; j < 4; ++j)
        acc[i][j] = __builtin_amdgcn_mfma_f32_16x16x32_bf16(afr[cbk][i], bfr[cbk][j], acc[i][j], 0, 0, 0);
    __builtin_amdgcn_s_setprio(0);
    // boundary: drain stage(kt+2) (needed next body), keep stage(kt+3) in flight
    if (kt < 5)       asm volatile("s_waitcnt vmcnt(4)" ::: "memory");
    else if (kt == 5) asm volatile("s_waitcnt vmcnt(0)" ::: "memory");
    if (kt < 7) {
      asm volatile("" ::: "memory");
      __builtin_amdgcn_s_barrier();
      asm volatile("" ::: "memory");
    }
  }

  // ---- epilogue: fused argmin; ties -> smallest code; atomicMin (order-independent) ----
  float nrm[8][4];
#pragma unroll
  for (int i = 0; i < 8; ++i)
#pragma unroll
    for (int r = 0; r < 4; ++r)
      nrm[i][r] = norms[m0 + wm * 128 + i * 16 + g * 4 + r];

  u64* best2 = (u64*)lds;  // [256 zrows][2 wm] (slot0 region, long retired)
#pragma unroll
  for (int j = 0; j < 4; ++j) {
    float best = __builtin_inff();
    int bc = 0;
#pragma unroll
    for (int i = 0; i < 8; ++i)
#pragma unroll
      for (int r = 0; r < 4; ++r) {
        float sc = fmaf(acc[i][j][r], -2.0f, nrm[i][r]);
        int cd = m0 + wm * 128 + i * 16 + g * 4 + r;
        if (sc < best) { best = sc; bc = cd; }
      }
    uint32_t u = __float_as_uint(best);
    u ^= ((uint32_t)((int32_t)u >> 31) | 0x80000000u);  // monotone-sortable
    u64 p = ((u64)u << 32) | (uint32_t)bc;
#pragma unroll
    for (int off = 16; off < 64; off <<= 1) {
      u64 o = (u64)__shfl_xor((long long)p, off);
      p = o < p ? o : p;
    }
    if (lane < 16) best2[(size_t)(wn * 64 + j * 16 + lane) * 2 + wm] = p;
  }
  __syncthreads();
  if (tid < 256) {
    u64 a = best2[tid * 2], b = best2[tid * 2 + 1];
    u64 p = a < b ? a : b;
    atomicMin(&amin[n0 + tid], p);
  }
}

// ---- pack: amin u64 -> code u32 ----
__global__ __launch_bounds__(256) void pack_codes(const u64* __restrict__ amin,
                                                  uint32_t* __restrict__ codei)
{
  const int i = blockIdx.x * 1024 + threadIdx.x;
#pragma unroll
  for (int k = 0; k < 4; ++k) codei[i + k * 256] = (uint32_t)amin[i + k * 256];
}

// ---- gather + output + per-block loss partials (8 elems/thread) ----
__global__ __launch_bounds__(256) void gather_out(
    const float* __restrict__ z, const float* __restrict__ cb,
    const uint32_t* __restrict__ codei,
    float* __restrict__ out, float* __restrict__ partial)
{
  const int t = threadIdx.x;
  const size_t e0 = ((size_t)blockIdx.x * 256 + t) * 8;
  const int d = (int)((e0 >> 10) & 255);
  const int b = (int)(e0 >> 18);
  const int n0 = b * 1024 + (int)(e0 & 1023);
  uint4v k0 = *(const uint4v*)&codei[n0];
  uint4v k1 = *(const uint4v*)&codei[n0 + 4];
  floatx4 z0 = *(const floatx4*)&z[e0];
  floatx4 z1 = *(const floatx4*)&z[e0 + 4];
  floatx4 q0, q1;
#pragma unroll
  for (int m = 0; m < 4; ++m) {
    q0[m] = cb[((size_t)k0[m] << 8) + d];
    q1[m] = cb[((size_t)k1[m] << 8) + d];
  }
  *(floatx4*)&out[e0] = q0;
  *(floatx4*)&out[e0 + 4] = q1;
  float s = 0.f;
#pragma unroll
  for (int m = 0; m < 4; ++m) {
    float d0 = z0[m] - q0[m], d1 = z1[m] - q1[m];
    s += d0 * d0 + d1 * d1;
  }
#pragma unroll
  for (int off = 32; off; off >>= 1) s += __shfl_down(s, off);
  __shared__ float ps[4];
  if ((t & 63) == 0) ps[t >> 6] = s;
  __syncthreads();
  if (t == 0) partial[blockIdx.x] = ps[0] + ps[1] + ps[2] + ps[3];
}

// ---- deterministic final reduction + scalar outputs ----
__global__ __launch_bounds__(256) void finalize(const float* __restrict__ partial,
                                                float* __restrict__ out)
{
  const int t = threadIdx.x;
  float s = 0.f;
#pragma unroll
  for (int i = 0; i < 16; ++i) s += partial[i * 256 + t];
#pragma unroll
  for (int off = 32; off; off >>= 1) s += __shfl_down(s, off);
  __shared__ float ps[4];
  if ((t & 63) == 0) ps[t >> 6] = s;
  __syncthreads();
  if (t == 0) {
    float m = (ps[0] + ps[1] + ps[2] + ps[3]) / (float)QELEMS;
    out[QELEMS] = m;             // codebook_loss
    out[QELEMS + 1] = 0.2f * m;  // commitment_loss
  }
}

extern "C" void kernel_launch(void* const* d_in, const int* in_sizes, int n_in,
                              void* d_out, int out_size, void* d_ws, size_t ws_size,
                              hipStream_t stream)
{
  const float* z = (const float*)d_in[0];
  const float* cb = (const float*)d_in[1];
  float* out = (float*)d_out;
  char* ws = (char*)d_ws;

  // ws layout (bytes)
  __hip_bfloat16* zh = (__hip_bfloat16*)(ws + 0);          // 16,777,216
  __hip_bfloat16* chv = (__hip_bfloat16*)(ws + 16777216);  //  4,194,304
  float* norms = (float*)(ws + 20971520);                  //    131,072 (padded)
  u64* amin = (u64*)(ws + 21102592);                       //    262,144
  uint32_t* codei = (uint32_t*)(ws + 21364736);            //    131,072
  float* lpart = (float*)(ws + 21495808);                  //     16,384
  // total: 21,512,192 bytes

  prep_all<<<3088, 256, 0, stream>>>(z, cb, zh, chv, norms, amin);
  gemm_argmin<<<4096, 512, 0, stream>>>(zh, chv, norms, amin);
  pack_codes<<<32, 256, 0, stream>>>(amin, codei);
  gather_out<<<QELEMS / 2048, 256, 0, stream>>>(z, cb, codei, out, lpart);
  finalize<<<1, 256, 0, stream>>>(lpart, out);
}

// Round 8
// 220.561 us; speedup vs baseline: 1.0368x; 1.0368x over previous
//
#include <hip/hip_runtime.h>
#include <hip/hip_bf16.h>
#include <stdint.h>

typedef __attribute__((ext_vector_type(8))) short short8;
typedef __attribute__((ext_vector_type(4))) short short4v;
typedef __attribute__((ext_vector_type(4))) float floatx4;
typedef __attribute__((ext_vector_type(4))) unsigned int uint4v;
typedef unsigned long long u64;

typedef __attribute__((address_space(1))) const uint32_t ga_u32;
typedef __attribute__((address_space(3))) uint32_t ls_u32;

static constexpr int NROWS = 32768;
static constexpr int NCODE = 8192;
static constexpr int QELEMS = 8388608;

static __device__ __forceinline__ short bf16bits(float v) {
  __hip_bfloat16 h = __float2bfloat16(v);
  return *reinterpret_cast<short*>(&h);
}

// ---- fused prep: [0,1024) z-transpose, [1024,3072) codebook, [3072,3088) amin init ----
__global__ __launch_bounds__(256) void prep_all(
    const float* __restrict__ z, const float* __restrict__ cb,
    __hip_bfloat16* __restrict__ zh, __hip_bfloat16* __restrict__ chv,
    float* __restrict__ norms, u64* __restrict__ amin)
{
  const int bid = blockIdx.x;
  const int t = threadIdx.x;
  if (bid < 1024) {
    __shared__ float tile[32][260];
    const int b = bid & 31, db = (bid >> 5) & 7, hwb = bid >> 8;
    const int d0 = db * 32, hw0 = hwb * 256;
    const float* src = z + (((size_t)b * 256 + d0) << 10) + hw0;
#pragma unroll
    for (int i = 0; i < 8; ++i) {
      int idx = i * 256 + t;
      int r = idx >> 6, c4 = (idx & 63) * 4;
      *(floatx4*)&tile[r][c4] = *(const floatx4*)&src[((size_t)r << 10) + c4];
    }
    __syncthreads();
    const int dq = t & 3;
    const int hb = t >> 2;
#pragma unroll
    for (int it = 0; it < 4; ++it) {
      int h = hb + it * 64;
      short8 o;
#pragma unroll
      for (int i = 0; i < 8; ++i) o[i] = bf16bits(tile[dq * 8 + i][h]);
      *(short8*)&zh[((size_t)(b * 1024 + hw0 + h)) * 256 + d0 + dq * 8] = o;
    }
  } else if (bid < 3072) {
    const int k = (bid - 1024) * 4 + (t >> 6);
    const int lane = t & 63;
    floatx4 v = *(const floatx4*)&cb[((size_t)k << 8) + lane * 4];
    short4v o;
#pragma unroll
    for (int i = 0; i < 4; ++i) o[i] = bf16bits(v[i]);
    *(short4v*)&chv[((size_t)k << 8) + lane * 4] = o;
    float s = v[0] * v[0] + v[1] * v[1] + v[2] * v[2] + v[3] * v[3];
#pragma unroll
    for (int off = 32; off; off >>= 1) s += __shfl_down(s, off);
    if (lane == 0) norms[k] = s;
  } else {
    const int base = (bid - 3072) * 2048;
#pragma unroll
    for (int i = 0; i < 8; ++i) amin[base + i * 256 + t] = ~0ull;
  }
}

// ---- main: 256x256 tile, BK=64, 2 LDS buffers, 4 fine phases per K-tile ----
// Phase = {ds_read burst (0-12) | stage 1 group -> barrier -> lgkmcnt(0) ->
// setprio 16-MFMA quadrant -> counted vmcnt -> barrier}. Stage groups are
// consumption-ordered so steady-state waits are vmcnt(4), never 0 (tail only).
__global__ __launch_bounds__(512, 2) void gemm_argmin(
    const __hip_bfloat16* __restrict__ zh, const __hip_bfloat16* __restrict__ chv,
    const float* __restrict__ norms, u64* __restrict__ amin)
{
  // buffer b at b*32768: A[256][64] bf16 at +0, B[256][64] at +16384 (ushorts)
  __shared__ alignas(16) unsigned short lds[2 * 32768];

  const int tid = threadIdx.x;
  const int lane = tid & 63;
  const int wid = tid >> 6;
  const int wm = wid >> 2;  // code half (128 codes)
  const int wn = wid & 3;   // zrow quarter (64 zrows)

  // XCD chunked swizzle: nwg = 4096 (%8 == 0)
  const int bid = blockIdx.x;
  const int swz = (bid & 7) * 512 + (bid >> 3);
  const int cx = swz & 31;
  const int cy = swz >> 5;
  const int m0 = cx * 256;
  const int n0 = cy * 256;

  const int q = lane & 15;
  const int g = lane >> 4;
  const int q7 = q & 7;

  floatx4 acc[8][4];  // [code frag i][zrow frag j]
#pragma unroll
  for (int i = 0; i < 8; ++i)
#pragma unroll
    for (int j = 0; j < 4; ++j)
      acc[i][j] = (floatx4){0.f, 0.f, 0.f, 0.f};

  // stage one 16-KB group (2 x global_load_lds per thread). Groups:
  // 0 = A rows {0-63,128-191}, 1 = B rows {wn*64+0..31}, 2 = B rows {wn*64+32..63},
  // 3 = A rows {64-127,192-255}. Linear LDS dest == row-major position; global
  // source chunk pre-swizzled: sc = (l&7)^(l>>3)  (rows within chunk are 8-aligned).
  auto STAGE = [&](int kt, int grp) {
    if (kt >= 4) return;
    const int buf = kt & 1;
    const bool isA = (grp == 0 || grp == 3);
    const __hip_bfloat16* src = isA ? chv : zh;
    const int tile0 = isA ? m0 : n0;
    unsigned short* region = lds + buf * 32768 + (isA ? 0 : 16384);
    const int sc = (lane & 7) ^ ((lane >> 3) & 7);
#pragma unroll
    for (int L = 0; L < 2; ++L) {
      int fr = (L * 8 + wid) * 8 + (lane >> 3);  // 0..127 flat row in group
      int r;
      if (grp == 0)      r = ((fr >> 6) << 7) + (fr & 63);
      else if (grp == 3) r = ((fr >> 6) << 7) + 64 + (fr & 63);
      else if (grp == 1) r = ((fr >> 5) << 6) + (fr & 31);
      else               r = ((fr >> 5) << 6) + 32 + (fr & 31);
      const __hip_bfloat16* gp = src + ((size_t)(tile0 + r) << 8) + kt * 64 + sc * 8;
      __builtin_amdgcn_global_load_lds((ga_u32*)gp,
          (ls_u32*)(region + r * 64 + (lane & 7) * 8), 16, 0, 0);
    }
  };
  auto LDA = [&](int kt, int ihalf, int i2, int kk) -> short8 {
    int row = wm * 128 + ihalf * 64 + i2 * 16 + q;
    int ch = ((kk << 2) | g) ^ q7;
    return *(const short8*)(lds + (kt & 1) * 32768 + row * 64 + ch * 8);
  };
  auto LDB = [&](int kt, int j, int kk) -> short8 {
    int row = wn * 64 + j * 16 + q;
    int ch = ((kk << 2) | g) ^ q7;
    return *(const short8*)(lds + (kt & 1) * 32768 + 16384 + row * 64 + ch * 8);
  };

  // prologue: stage kt0's 4 groups; drain groups 0,1 (A0,B01); 2 groups in flight
  STAGE(0, 0); STAGE(0, 1); STAGE(0, 2); STAGE(0, 3);
  asm volatile("s_waitcnt vmcnt(4)" ::: "memory");
  __builtin_amdgcn_s_barrier();
  asm volatile("" ::: "memory");

  short8 afr[4][2], b01[2][2], b23[2][2];

#pragma unroll
  for (int kt = 0; kt < 4; ++kt) {
    // ======== P1: read A-half0 (8) + B j0-1 (4); stage A0(kt+1); MFMA (i0-3 x j0-1) ========
#pragma unroll
    for (int i2 = 0; i2 < 4; ++i2)
#pragma unroll
      for (int kk = 0; kk < 2; ++kk) afr[i2][kk] = LDA(kt, 0, i2, kk);
#pragma unroll
    for (int jj = 0; jj < 2; ++jj)
#pragma unroll
      for (int kk = 0; kk < 2; ++kk) b01[jj][kk] = LDB(kt, jj, kk);
    STAGE(kt + 1, 0);
    asm volatile("" ::: "memory");
    __builtin_amdgcn_s_barrier();
    asm volatile("s_waitcnt lgkmcnt(0)" ::: "memory");
    __builtin_amdgcn_sched_barrier(0);
    __builtin_amdgcn_s_setprio(1);
#pragma unroll
    for (int i2 = 0; i2 < 4; ++i2)
#pragma unroll
      for (int jj = 0; jj < 2; ++jj)
#pragma unroll
        for (int kk = 0; kk < 2; ++kk)
          acc[i2][jj] = __builtin_amdgcn_mfma_f32_16x16x32_bf16(afr[i2][kk], b01[jj][kk], acc[i2][jj], 0, 0, 0);
    __builtin_amdgcn_s_setprio(0);
    if (kt < 3) asm volatile("s_waitcnt vmcnt(4)" ::: "memory");  // drains B23(kt)
    else        asm volatile("s_waitcnt vmcnt(2)" ::: "memory");
    asm volatile("" ::: "memory");
    __builtin_amdgcn_s_barrier();
    asm volatile("" ::: "memory");

    // ======== P2: read B j2-3 (4); stage B01(kt+1); MFMA (i0-3 x j2-3) ========
#pragma unroll
    for (int jj = 0; jj < 2; ++jj)
#pragma unroll
      for (int kk = 0; kk < 2; ++kk) b23[jj][kk] = LDB(kt, 2 + jj, kk);
    STAGE(kt + 1, 1);
    asm volatile("" ::: "memory");
    __builtin_amdgcn_s_barrier();
    asm volatile("s_waitcnt lgkmcnt(0)" ::: "memory");
    __builtin_amdgcn_sched_barrier(0);
    __builtin_amdgcn_s_setprio(1);
#pragma unroll
    for (int i2 = 0; i2 < 4; ++i2)
#pragma unroll
      for (int jj = 0; jj < 2; ++jj)
#pragma unroll
        for (int kk = 0; kk < 2; ++kk)
          acc[i2][2 + jj] = __builtin_amdgcn_mfma_f32_16x16x32_bf16(afr[i2][kk], b23[jj][kk], acc[i2][2 + jj], 0, 0, 0);
    __builtin_amdgcn_s_setprio(0);
    if (kt < 3) asm volatile("s_waitcnt vmcnt(4)" ::: "memory");  // drains A1(kt)
    else        asm volatile("s_waitcnt vmcnt(0)" ::: "memory");
    asm volatile("" ::: "memory");
    __builtin_amdgcn_s_barrier();
    asm volatile("" ::: "memory");

    // ======== P3: read A-half1 (8); stage B23(kt+1); MFMA (i4-7 x j2-3) ========
#pragma unroll
    for (int i2 = 0; i2 < 4; ++i2)
#pragma unroll
      for (int kk = 0; kk < 2; ++kk) afr[i2][kk] = LDA(kt, 1, i2, kk);
    STAGE(kt + 1, 2);
    asm volatile("" ::: "memory");
    __builtin_amdgcn_s_barrier();
    asm volatile("s_waitcnt lgkmcnt(0)" ::: "memory");
    __builtin_amdgcn_sched_barrier(0);
    __builtin_amdgcn_s_setprio(1);
#pragma unroll
    for (int i2 = 0; i2 < 4; ++i2)
#pragma unroll
      for (int jj = 0; jj < 2; ++jj)
#pragma unroll
        for (int kk = 0; kk < 2; ++kk)
          acc[4 + i2][2 + jj] = __builtin_amdgcn_mfma_f32_16x16x32_bf16(afr[i2][kk], b23[jj][kk], acc[4 + i2][2 + jj], 0, 0, 0);
    __builtin_amdgcn_s_setprio(0);
    asm volatile("" ::: "memory");   // P4 reads nothing from LDS: no vmcnt here
    __builtin_amdgcn_s_barrier();
    asm volatile("" ::: "memory");

    // ======== P4: stage A1(kt+1); MFMA (i4-7 x j0-1) on retained b01 ========
    STAGE(kt + 1, 3);
    asm volatile("" ::: "memory");
    __builtin_amdgcn_s_barrier();
    asm volatile("" ::: "memory");
    __builtin_amdgcn_s_setprio(1);
#pragma unroll
    for (int i2 = 0; i2 < 4; ++i2)
#pragma unroll
      for (int jj = 0; jj < 2; ++jj)
#pragma unroll
        for (int kk = 0; kk < 2; ++kk)
          acc[4 + i2][jj] = __builtin_amdgcn_mfma_f32_16x16x32_bf16(afr[i2][kk], b01[jj][kk], acc[4 + i2][jj], 0, 0, 0);
    __builtin_amdgcn_s_setprio(0);
    if (kt < 3) {
      asm volatile("s_waitcnt vmcnt(4)" ::: "memory");  // drains A0,B01(kt+1)
      asm volatile("" ::: "memory");
      __builtin_amdgcn_s_barrier();
      asm volatile("" ::: "memory");
    }
  }

  __syncthreads();  // all waves past final MFMA before LDS reuse

  // ---- epilogue: fused argmin; ties -> smallest code; atomicMin (order-independent) ----
  float nrm[8][4];
#pragma unroll
  for (int i = 0; i < 8; ++i)
#pragma unroll
    for (int r = 0; r < 4; ++r)
      nrm[i][r] = norms[m0 + wm * 128 + i * 16 + g * 4 + r];

  u64* best2 = (u64*)lds;  // [256 zrows][2 wm]
#pragma unroll
  for (int j = 0; j < 4; ++j) {
    float best = __builtin_inff();
    int bc = 0;
#pragma unroll
    for (int i = 0; i < 8; ++i)
#pragma unroll
      for (int r = 0; r < 4; ++r) {
        float sc = fmaf(acc[i][j][r], -2.0f, nrm[i][r]);
        int cd = m0 + wm * 128 + i * 16 + g * 4 + r;
        if (sc < best) { best = sc; bc = cd; }
      }
    uint32_t u = __float_as_uint(best);
    u ^= ((uint32_t)((int32_t)u >> 31) | 0x80000000u);  // monotone-sortable
    u64 p = ((u64)u << 32) | (uint32_t)bc;
#pragma unroll
    for (int off = 16; off < 64; off <<= 1) {
      u64 o = (u64)__shfl_xor((long long)p, off);
      p = o < p ? o : p;
    }
    if (lane < 16) best2[(size_t)(wn * 64 + j * 16 + lane) * 2 + wm] = p;
  }
  __syncthreads();
  if (tid < 256) {
    u64 a = best2[tid * 2], b = best2[tid * 2 + 1];
    u64 p = a < b ? a : b;
    atomicMin(&amin[n0 + tid], p);
  }
}

// ---- pack: amin u64 -> code u32 ----
__global__ __launch_bounds__(256) void pack_codes(const u64* __restrict__ amin,
                                                  uint32_t* __restrict__ codei)
{
  const int i = blockIdx.x * 1024 + threadIdx.x;
#pragma unroll
  for (int k = 0; k < 4; ++k) codei[i + k * 256] = (uint32_t)amin[i + k * 256];
}

// ---- gather + output + per-block loss partials (8 elems/thread) ----
__global__ __launch_bounds__(256) void gather_out(
    const float* __restrict__ z, const float* __restrict__ cb,
    const uint32_t* __restrict__ codei,
    float* __restrict__ out, float* __restrict__ partial)
{
  const int t = threadIdx.x;
  const size_t e0 = ((size_t)blockIdx.x * 256 + t) * 8;
  const int d = (int)((e0 >> 10) & 255);
  const int b = (int)(e0 >> 18);
  const int n0 = b * 1024 + (int)(e0 & 1023);
  uint4v k0 = *(const uint4v*)&codei[n0];
  uint4v k1 = *(const uint4v*)&codei[n0 + 4];
  floatx4 z0 = *(const floatx4*)&z[e0];
  floatx4 z1 = *(const floatx4*)&z[e0 + 4];
  floatx4 q0, q1;
#pragma unroll
  for (int m = 0; m < 4; ++m) {
    q0[m] = cb[((size_t)k0[m] << 8) + d];
    q1[m] = cb[((size_t)k1[m] << 8) + d];
  }
  *(floatx4*)&out[e0] = q0;
  *(floatx4*)&out[e0 + 4] = q1;
  float s = 0.f;
#pragma unroll
  for (int m = 0; m < 4; ++m) {
    float d0 = z0[m] - q0[m], d1 = z1[m] - q1[m];
    s += d0 * d0 + d1 * d1;
  }
#pragma unroll
  for (int off = 32; off; off >>= 1) s += __shfl_down(s, off);
  __shared__ float ps[4];
  if ((t & 63) == 0) ps[t >> 6] = s;
  __syncthreads();
  if (t == 0) partial[blockIdx.x] = ps[0] + ps[1] + ps[2] + ps[3];
}

// ---- deterministic final reduction + scalar outputs ----
__global__ __launch_bounds__(256) void finalize(const float* __restrict__ partial,
                                                float* __restrict__ out)
{
  const int t = threadIdx.x;
  float s = 0.f;
#pragma unroll
  for (int i = 0; i < 16; ++i) s += partial[i * 256 + t];
#pragma unroll
  for (int off = 32; off; off >>= 1) s += __shfl_down(s, off);
  __shared__ float ps[4];
  if ((t & 63) == 0) ps[t >> 6] = s;
  __syncthreads();
  if (t == 0) {
    float m = (ps[0] + ps[1] + ps[2] + ps[3]) / (float)QELEMS;
    out[QELEMS] = m;             // codebook_loss
    out[QELEMS + 1] = 0.2f * m;  // commitment_loss
  }
}

extern "C" void kernel_launch(void* const* d_in, const int* in_sizes, int n_in,
                              void* d_out, int out_size, void* d_ws, size_t ws_size,
                              hipStream_t stream)
{
  const float* z = (const float*)d_in[0];
  const float* cb = (const float*)d_in[1];
  float* out = (float*)d_out;
  char* ws = (char*)d_ws;

  // ws layout (bytes)
  __hip_bfloat16* zh = (__hip_bfloat16*)(ws + 0);          // 16,777,216
  __hip_bfloat16* chv = (__hip_bfloat16*)(ws + 16777216);  //  4,194,304
  float* norms = (float*)(ws + 20971520);                  //    131,072 (padded)
  u64* amin = (u64*)(ws + 21102592);                       //    262,144
  uint32_t* codei = (uint32_t*)(ws + 21364736);            //    131,072
  float* lpart = (float*)(ws + 21495808);                  //     16,384
  // total: 21,512,192 bytes

  prep_all<<<3088, 256, 0, stream>>>(z, cb, zh, chv, norms, amin);
  gemm_argmin<<<4096, 512, 0, stream>>>(zh, chv, norms, amin);
  pack_codes<<<32, 256, 0, stream>>>(amin, codei);
  gather_out<<<QELEMS / 2048, 256, 0, stream>>>(z, cb, codei, out, lpart);
  finalize<<<1, 256, 0, stream>>>(lpart, out);
}